// Round 2
// baseline (580.019 us; speedup 1.0000x reference)
//
#include <hip/hip_runtime.h>
#include <hip/hip_bf16.h>

#define NN 8192
#define DIN 128
#define DOUT 128

typedef __bf16 bf16;
typedef __bf16 bf16x4 __attribute__((ext_vector_type(4)));
typedef __bf16 bf16x8 __attribute__((ext_vector_type(8)));
typedef float f32x4 __attribute__((ext_vector_type(4)));

// ---- K1: rowsum -> dinv, and adj fp32 -> bf16 copy (fused, one pass) ----
// 1 row per block, 256 threads. 8 float4 loads/thread (low VGPR -> high occ).
__global__ __launch_bounds__(256) void k1_rowsum_cvt(const float* __restrict__ adj,
                                                     float* __restrict__ dinv,
                                                     bf16* __restrict__ adjb) {
    int row = blockIdx.x;
    int t   = threadIdx.x;
    const float4* p = reinterpret_cast<const float4*>(adj + (size_t)row * NN);
    bf16x4* q = reinterpret_cast<bf16x4*>(adjb + (size_t)row * NN);
    float s = 0.f;
    #pragma unroll
    for (int i = 0; i < 8; ++i) {
        float4 v = p[t + i * 256];
        bf16x4 b = { (bf16)v.x, (bf16)v.y, (bf16)v.z, (bf16)v.w };
        q[t + i * 256] = b;                    // 512 B/wave-inst, coalesced
        s += (v.x + v.y) + (v.z + v.w);
    }
    #pragma unroll
    for (int off = 32; off > 0; off >>= 1) s += __shfl_down(s, off, 64);
    __shared__ float r4[4];
    if ((t & 63) == 0) r4[t >> 6] = s;
    __syncthreads();
    if (t == 0) dinv[row] = rsqrtf(((r4[0] + r4[1]) + (r4[2] + r4[3])) + 1e-6f);
}

// ---- K2: yT[c][j] = bf16(dinv[j] * x[j][c])  (transposed for MFMA-B) ----
__global__ __launch_bounds__(256) void k2_transpose(const float* __restrict__ x,
                                                    const float* __restrict__ dinv,
                                                    bf16* __restrict__ yT) {
    __shared__ bf16 T[DIN][136];
    __shared__ float dl[128];
    int t  = threadIdx.x;
    int j0 = blockIdx.x * 128;
    if (t < 128) dl[t] = dinv[j0 + t];
    __syncthreads();
    #pragma unroll
    for (int s = 0; s < 16; ++s) {
        int i  = t + s * 256;
        int j  = i >> 5;
        int c4 = i & 31;
        float4 v = *reinterpret_cast<const float4*>(x + (size_t)(j0 + j) * DIN + c4 * 4);
        float d = dl[j];
        T[c4 * 4 + 0][j] = (bf16)(v.x * d);
        T[c4 * 4 + 1][j] = (bf16)(v.y * d);
        T[c4 * 4 + 2][j] = (bf16)(v.z * d);
        T[c4 * 4 + 3][j] = (bf16)(v.w * d);
    }
    __syncthreads();
    #pragma unroll
    for (int s = 0; s < 8; ++s) {
        int i  = t + s * 256;
        int c  = i >> 4;
        int j8 = i & 15;
        *reinterpret_cast<uint4*>(yT + (size_t)c * NN + j0 + j8 * 8) =
            *reinterpret_cast<const uint4*>(&T[c][j8 * 8]);
    }
}

// ---- K3: hp[split] = adjb[rows, ksplit] @ y[ksplit, :]  (bf16 MFMA) -----
// BM=32, BK=64, BN=128, split-K=4 -> 1024 blocks (4/CU, 16 waves/CU).
// Register prefetch of next tile overlaps HBM latency with MFMA.
#define LDA 72   // bf16; 144 B row stride (9x16B). 8-lane b128 phases are
#define LDB 72   // contiguous 128 B -> conflict-free reads & writes.

__global__ __launch_bounds__(256) void k3_gemm(const bf16* __restrict__ adjb,
                                               const bf16* __restrict__ yT,
                                               float* __restrict__ hp) {
    __shared__ bf16 Asm[32 * LDA];
    __shared__ bf16 Bsm[128 * LDB];
    int t     = threadIdx.x;
    int mb    = blockIdx.x >> 2;
    int split = blockIdx.x & 3;
    int m0    = mb * 32;
    int k0    = split * 2048;
    int lane  = t & 63;
    int wn    = t >> 6;
    int mrow  = lane & 15;
    int quad  = lane >> 4;

    int arow = t >> 3;            // 0..31 (A row / B row-group base)
    int ac8  = t & 7;             // 16B chunk within 64-elem k-slice

    f32x4 acc[2][2] = {};

    const bf16* ap = adjb + (size_t)(m0 + arow) * NN + k0 + ac8 * 8;
    const bf16* bp = yT + (size_t)arow * NN + k0 + ac8 * 8;

    // prefetch tile 0
    uint4 av = *reinterpret_cast<const uint4*>(ap);
    uint4 bv[4];
    #pragma unroll
    for (int s = 0; s < 4; ++s)
        bv[s] = *reinterpret_cast<const uint4*>(bp + (size_t)(s * 32) * NN);

    for (int kk = 0; kk < 32; ++kk) {
        __syncthreads();          // previous compute done reading LDS
        *reinterpret_cast<uint4*>(&Asm[arow * LDA + ac8 * 8]) = av;
        #pragma unroll
        for (int s = 0; s < 4; ++s)
            *reinterpret_cast<uint4*>(&Bsm[(arow + s * 32) * LDB + ac8 * 8]) = bv[s];
        if (kk < 31) {            // issue next loads; they fly during compute
            int col0 = (kk + 1) * 64;
            av = *reinterpret_cast<const uint4*>(ap + col0);
            #pragma unroll
            for (int s = 0; s < 4; ++s)
                bv[s] = *reinterpret_cast<const uint4*>(bp + (size_t)(s * 32) * NN + col0);
        }
        __syncthreads();
        #pragma unroll
        for (int ks = 0; ks < 2; ++ks) {
            bf16x8 af[2], bfr[2];
            #pragma unroll
            for (int mi = 0; mi < 2; ++mi)
                af[mi] = *reinterpret_cast<const bf16x8*>(
                    &Asm[(mi * 16 + mrow) * LDA + ks * 32 + quad * 8]);
            #pragma unroll
            for (int ni = 0; ni < 2; ++ni)
                bfr[ni] = *reinterpret_cast<const bf16x8*>(
                    &Bsm[(wn * 32 + ni * 16 + mrow) * LDB + ks * 32 + quad * 8]);
            #pragma unroll
            for (int mi = 0; mi < 2; ++mi)
                #pragma unroll
                for (int ni = 0; ni < 2; ++ni)
                    acc[mi][ni] = __builtin_amdgcn_mfma_f32_16x16x32_bf16(
                        af[mi], bfr[ni], acc[mi][ni], 0, 0, 0);
        }
    }
    // D[row=quad*4+reg][col=lane&15]
    float* out = hp + (size_t)split * (NN * DIN);
    #pragma unroll
    for (int mi = 0; mi < 2; ++mi)
        #pragma unroll
        for (int ni = 0; ni < 2; ++ni) {
            int col = wn * 32 + ni * 16 + mrow;
            #pragma unroll
            for (int r = 0; r < 4; ++r) {
                int row = m0 + mi * 16 + quad * 4 + r;
                out[(size_t)row * DIN + col] = acc[mi][ni][r];
            }
        }
}

// ---- K4: out = (sum_s hp[s]) * dinv[i] @ W^T + b  (fp32 vector) ---------
__global__ __launch_bounds__(256) void k4_out(const float* __restrict__ hp,
                                              const float* __restrict__ dinv,
                                              const float* __restrict__ W,
                                              const float* __restrict__ bias,
                                              float* __restrict__ out) {
    __shared__ float Wl[128 * 132];
    __shared__ float hl[32 * 132];
    __shared__ float bl[128];
    int t  = threadIdx.x;
    int i0 = blockIdx.x * 32;
    if (t < 128) bl[t] = bias[t];
    #pragma unroll
    for (int s = 0; s < 16; ++s) {
        int i  = t + s * 256;
        int o  = i >> 5;
        int c4 = i & 31;
        *reinterpret_cast<float4*>(&Wl[o * 132 + c4 * 4]) =
            *reinterpret_cast<const float4*>(W + o * 128 + c4 * 4);
    }
    #pragma unroll
    for (int s = 0; s < 4; ++s) {
        int i   = t + s * 256;
        int row = i >> 5;
        int c4  = i & 31;
        size_t g = (size_t)(i0 + row) * DIN + c4 * 4;
        float4 a0 = *reinterpret_cast<const float4*>(hp + g);
        float4 a1 = *reinterpret_cast<const float4*>(hp + (size_t)NN * DIN + g);
        float4 a2 = *reinterpret_cast<const float4*>(hp + (size_t)2 * NN * DIN + g);
        float4 a3 = *reinterpret_cast<const float4*>(hp + (size_t)3 * NN * DIN + g);
        float d = dinv[i0 + row];
        float4 hv = { ((a0.x + a1.x) + (a2.x + a3.x)) * d,
                      ((a0.y + a1.y) + (a2.y + a3.y)) * d,
                      ((a0.z + a1.z) + (a2.z + a3.z)) * d,
                      ((a0.w + a1.w) + (a2.w + a3.w)) * d };
        *reinterpret_cast<float4*>(&hl[row * 132 + c4 * 4]) = hv;
    }
    __syncthreads();
    int o = t & 127;
    int g = t >> 7;
    float acc[16];
    #pragma unroll
    for (int r = 0; r < 16; ++r) acc[r] = bl[o];
    for (int c4 = 0; c4 < 32; ++c4) {
        float4 w4 = *reinterpret_cast<const float4*>(&Wl[o * 132 + c4 * 4]);
        #pragma unroll
        for (int r = 0; r < 16; ++r) {
            float4 h4 = *reinterpret_cast<const float4*>(&hl[(g * 16 + r) * 132 + c4 * 4]);
            acc[r] += h4.x * w4.x + h4.y * w4.y + h4.z * w4.z + h4.w * w4.w;
        }
    }
    #pragma unroll
    for (int r = 0; r < 16; ++r)
        out[(size_t)(i0 + g * 16 + r) * DOUT + o] = acc[r];
}

extern "C" void kernel_launch(void* const* d_in, const int* in_sizes, int n_in,
                              void* d_out, int out_size, void* d_ws, size_t ws_size,
                              hipStream_t stream) {
    const float* x   = (const float*)d_in[0];
    const float* adj = (const float*)d_in[1];
    const float* W   = (const float*)d_in[2];
    const float* b   = (const float*)d_in[3];
    float* out = (float*)d_out;
    char* ws = (char*)d_ws;
    float* dinv = (float*)ws;                   // 32 KB    @ 0
    bf16*  yT   = (bf16*)(ws + (1u << 20));     // 2 MB     @ 1 MB
    float* hp   = (float*)(ws + (4u << 20));    // 4x4 MB   @ 4 MB
    bf16*  adjb = (bf16*)(ws + (32u << 20));    // 128 MB   @ 32 MB

    k1_rowsum_cvt<<<NN, 256, 0, stream>>>(adj, dinv, adjb);
    k2_transpose <<<NN / 128, 256, 0, stream>>>(x, dinv, yT);
    k3_gemm      <<<(NN / 32) * 4, 256, 0, stream>>>(adjb, yT, hp);
    k4_out       <<<NN / 32, 256, 0, stream>>>(hp, dinv, W, b, out);
}

// Round 3
// 464.930 us; speedup vs baseline: 1.2475x; 1.2475x over previous
//
#include <hip/hip_runtime.h>
#include <hip/hip_bf16.h>

#define NN 8192
#define DIN 128
#define DOUT 128

typedef __bf16 bf16;
typedef __bf16 bf16x8 __attribute__((ext_vector_type(8)));
typedef float f32x4 __attribute__((ext_vector_type(4)));

// ---- K1: rowsum -> dinv[i] = rsqrt(sum(adj[i,:]) + eps). Pure stream. ----
__global__ __launch_bounds__(256) void k1_rowsum(const float* __restrict__ adj,
                                                 float* __restrict__ dinv) {
    int row = blockIdx.x;
    int t   = threadIdx.x;
    const float4* p = reinterpret_cast<const float4*>(adj + (size_t)row * NN);
    float s = 0.f;
    #pragma unroll
    for (int i = 0; i < 8; ++i) {
        float4 v = p[t + i * 256];
        s += (v.x + v.y) + (v.z + v.w);
    }
    #pragma unroll
    for (int off = 32; off > 0; off >>= 1) s += __shfl_down(s, off, 64);
    __shared__ float r4[4];
    if ((t & 63) == 0) r4[t >> 6] = s;
    __syncthreads();
    if (t == 0) dinv[row] = rsqrtf(((r4[0] + r4[1]) + (r4[2] + r4[3])) + 1e-6f);
}

// ---- K2: z = x @ W^T;  yT[c][j] = bf16(dinv[j] * z[j][c])  (transposed) --
// 32 x-rows per block, fp32 vector dot (268 MFLOP total — tiny).
__global__ __launch_bounds__(256) void k2_xwT(const float* __restrict__ x,
                                              const float* __restrict__ W,
                                              const float* __restrict__ dinv,
                                              bf16* __restrict__ yT) {
    __shared__ float Wl[128 * 132];
    __shared__ float xl[32 * 132];
    __shared__ float dl[32];
    int t  = threadIdx.x;
    int i0 = blockIdx.x * 32;
    if (t < 32) dl[t] = dinv[i0 + t];
    #pragma unroll
    for (int s = 0; s < 16; ++s) {
        int i  = t + s * 256;
        int o  = i >> 5;
        int c4 = i & 31;
        *reinterpret_cast<float4*>(&Wl[o * 132 + c4 * 4]) =
            *reinterpret_cast<const float4*>(W + o * 128 + c4 * 4);
    }
    #pragma unroll
    for (int s = 0; s < 4; ++s) {
        int i   = t + s * 256;
        int row = i >> 5;
        int c4  = i & 31;
        *reinterpret_cast<float4*>(&xl[row * 132 + c4 * 4]) =
            *reinterpret_cast<const float4*>(x + (size_t)(i0 + row) * DIN + c4 * 4);
    }
    __syncthreads();
    int o = t & 127;          // output feature (column of z, row of yT)
    int g = t >> 7;           // row group: rows g*16 .. g*16+15
    float acc[16] = {};
    for (int c4 = 0; c4 < 32; ++c4) {
        float4 w4 = *reinterpret_cast<const float4*>(&Wl[o * 132 + c4 * 4]);
        #pragma unroll
        for (int r = 0; r < 16; ++r) {
            float4 h4 = *reinterpret_cast<const float4*>(&xl[(g * 16 + r) * 132 + c4 * 4]);
            acc[r] += h4.x * w4.x + h4.y * w4.y + h4.z * w4.z + h4.w * w4.w;
        }
    }
    // yT[o][i0 + g*16 + r] = bf16(dinv * z): 16 contiguous bf16 = 2 x 16B
    bf16x8 o0, o1;
    #pragma unroll
    for (int r = 0; r < 8; ++r) o0[r] = (bf16)(acc[r] * dl[g * 16 + r]);
    #pragma unroll
    for (int r = 0; r < 8; ++r) o1[r] = (bf16)(acc[8 + r] * dl[g * 16 + 8 + r]);
    bf16* dst = yT + (size_t)o * NN + i0 + g * 16;
    *reinterpret_cast<bf16x8*>(dst)     = o0;
    *reinterpret_cast<bf16x8*>(dst + 8) = o1;
}

// ---- K0b: out[i][c] = bias[c]  (atomic accumulation target) --------------
__global__ __launch_bounds__(256) void k0_init(const float* __restrict__ bias,
                                               float* __restrict__ out) {
    int g = blockIdx.x * 256 + threadIdx.x;        // float4 index
    float4 b4 = *reinterpret_cast<const float4*>(bias + (threadIdx.x & 31) * 4);
    *reinterpret_cast<float4*>(out + (size_t)g * 4) = b4;
}

// ---- K3: out += dinv[i] * (adj[i, ksplit] @ y[ksplit, :])  ---------------
// Barrier-free streaming MFMA: B-slice (128 x 512 bf16) resident in LDS,
// A read fp32 from global straight into fragments (no LDS staging, no
// per-iter barriers). Split-K=16 via native f32 atomics onto bias-init out.
#define KR 512
#define LDB3 520   // 1040 B row stride: 16B-aligned, conflict-free b128

__global__ __launch_bounds__(512, 2) void k3_spmm(const float* __restrict__ adj,
                                                  const bf16* __restrict__ yT,
                                                  const float* __restrict__ dinv,
                                                  float* __restrict__ out) {
    __shared__ bf16 BL[128 * LDB3];   // 130 KB
    int t     = threadIdx.x;
    int split = blockIdx.x & 15;
    int mg    = blockIdx.x >> 4;
    int m0    = mg * 256;
    int k0    = split * KR;
    // stage B once: 128 rows x 512 bf16 (64 x 16B chunks per row)
    for (int i = t; i < 128 * 64; i += 512) {
        int c = i >> 6, ch = i & 63;
        *reinterpret_cast<uint4*>(&BL[c * LDB3 + ch * 8]) =
            *reinterpret_cast<const uint4*>(yT + (size_t)c * NN + k0 + ch * 8);
    }
    __syncthreads();                  // the only barrier

    int wave = t >> 6, lane = t & 63;
    int mrow = lane & 15, quad = lane >> 4;
    int wm0  = wave * 32 + m0;        // this wave's 32-row strip pair

    f32x4 dv0 = *reinterpret_cast<const f32x4*>(dinv + wm0 + quad * 4);
    f32x4 dv1 = *reinterpret_cast<const f32x4*>(dinv + wm0 + 16 + quad * 4);

    f32x4 acc[2][8] = {};
    const float* a0p = adj + (size_t)(wm0 + mrow) * NN + k0 + quad * 8;
    const float* a1p = a0p + (size_t)16 * NN;

    float4 c0a = *(const float4*)a0p;       float4 c0b = *(const float4*)(a0p + 4);
    float4 c1a = *(const float4*)a1p;       float4 c1b = *(const float4*)(a1p + 4);

    for (int kk = 0; kk < KR / 32; ++kk) {
        bf16x8 bf[8];
        int boff = kk * 32 + quad * 8;
        #pragma unroll
        for (int nt = 0; nt < 8; ++nt)
            bf[nt] = *reinterpret_cast<const bf16x8*>(&BL[(nt * 16 + mrow) * LDB3 + boff]);
        float4 n0a, n0b, n1a, n1b;
        if (kk < KR / 32 - 1) {            // prefetch next kstep (flies over MFMA)
            const float* p0 = a0p + (kk + 1) * 32;
            const float* p1 = a1p + (kk + 1) * 32;
            n0a = *(const float4*)p0; n0b = *(const float4*)(p0 + 4);
            n1a = *(const float4*)p1; n1b = *(const float4*)(p1 + 4);
        }
        bf16x8 af0 = { (bf16)c0a.x, (bf16)c0a.y, (bf16)c0a.z, (bf16)c0a.w,
                       (bf16)c0b.x, (bf16)c0b.y, (bf16)c0b.z, (bf16)c0b.w };
        bf16x8 af1 = { (bf16)c1a.x, (bf16)c1a.y, (bf16)c1a.z, (bf16)c1a.w,
                       (bf16)c1b.x, (bf16)c1b.y, (bf16)c1b.z, (bf16)c1b.w };
        #pragma unroll
        for (int nt = 0; nt < 8; ++nt) {
            acc[0][nt] = __builtin_amdgcn_mfma_f32_16x16x32_bf16(af0, bf[nt], acc[0][nt], 0, 0, 0);
            acc[1][nt] = __builtin_amdgcn_mfma_f32_16x16x32_bf16(af1, bf[nt], acc[1][nt], 0, 0, 0);
        }
        c0a = n0a; c0b = n0b; c1a = n1a; c1b = n1b;
    }
    // epilogue: D[row=quad*4+r][col=lane&15]; scale by dinv[row], atomic-add
    #pragma unroll
    for (int nt = 0; nt < 8; ++nt) {
        int col = nt * 16 + mrow;
        #pragma unroll
        for (int r = 0; r < 4; ++r) {
            unsafeAtomicAdd(out + (size_t)(wm0 + quad * 4 + r) * DOUT + col,
                            acc[0][nt][r] * dv0[r]);
            unsafeAtomicAdd(out + (size_t)(wm0 + 16 + quad * 4 + r) * DOUT + col,
                            acc[1][nt][r] * dv1[r]);
        }
    }
}

extern "C" void kernel_launch(void* const* d_in, const int* in_sizes, int n_in,
                              void* d_out, int out_size, void* d_ws, size_t ws_size,
                              hipStream_t stream) {
    const float* x   = (const float*)d_in[0];
    const float* adj = (const float*)d_in[1];
    const float* W   = (const float*)d_in[2];
    const float* b   = (const float*)d_in[3];
    float* out = (float*)d_out;
    char* ws = (char*)d_ws;
    float* dinv = (float*)ws;                   // 32 KB  @ 0
    bf16*  yT   = (bf16*)(ws + (1u << 20));     // 2 MB   @ 1 MB

    k1_rowsum<<<NN, 256, 0, stream>>>(adj, dinv);
    k2_xwT   <<<NN / 32, 256, 0, stream>>>(x, W, dinv, yT);
    k0_init  <<<(NN * DOUT / 4) / 256, 256, 0, stream>>>(b, out);
    k3_spmm  <<<16 * (NN / 256), 512, 0, stream>>>(adj, yT, dinv, out);
}